// Round 2
// baseline (304.612 us; speedup 1.0000x reference)
//
#include <hip/hip_runtime.h>
#include <hip/hip_bf16.h>
#include <stdint.h>

#define B_ROWS 1024
#define DIM    512
#define C_CLS  100000
#define C_PAD  100096          // 782 * 128
#define NT     782             // C_PAD / 128
#define MT     8               // B_ROWS / 128

using f32x4  = __attribute__((ext_vector_type(4))) float;
using bf16x8 = __attribute__((ext_vector_type(8))) short;   // 8 bf16 (4 VGPRs)

static __device__ __forceinline__ float bf2f(uint32_t u) { return __uint_as_float(u << 16); }
static __device__ __forceinline__ uint16_t f2bf(float f) {
    uint32_t u = __float_as_uint(f);
    u += 0x7fffu + ((u >> 16) & 1u);          // round-to-nearest-even
    return (uint16_t)(u >> 16);
}

// ---------- pass 1: per-row L2 normalize, f32 -> bf16; rows >= nvalid zeroed (pad)
__global__ __launch_bounds__(128) void normalize_rows(
    const float* __restrict__ src, uint16_t* __restrict__ dst, int nvalid)
{
    const int row = blockIdx.x;
    const int t   = threadIdx.x;               // 128 threads * 4 floats = 512
    uint16_t* drow = dst + (size_t)row * DIM;
    if (row >= nvalid) {
        reinterpret_cast<uint2*>(drow)[t] = make_uint2(0u, 0u);
        return;
    }
    const float4 v = reinterpret_cast<const float4*>(src + (size_t)row * DIM)[t];
    float ss = v.x*v.x + v.y*v.y + v.z*v.z + v.w*v.w;
    #pragma unroll
    for (int m = 1; m < 64; m <<= 1) ss += __shfl_xor(ss, m);
    __shared__ float red[2];
    if ((t & 63) == 0) red[t >> 6] = ss;
    __syncthreads();
    const float inv = 1.0f / fmaxf(sqrtf(red[0] + red[1]), 1e-12f);
    uint32_t p0 = (uint32_t)f2bf(v.x * inv) | ((uint32_t)f2bf(v.y * inv) << 16);
    uint32_t p1 = (uint32_t)f2bf(v.z * inv) | ((uint32_t)f2bf(v.w * inv) << 16);
    reinterpret_cast<uint2*>(drow)[t] = make_uint2(p0, p1);
}

// ---------- pass 2: 128x128 bf16 MFMA tile + per-row (max, sumexp) partials over its 128 cols
__global__ __launch_bounds__(256) void gemm_lse(
    const uint16_t* __restrict__ A,   // [B_ROWS][DIM]  normalized features bf16
    const uint16_t* __restrict__ W,   // [C_PAD][DIM]   normalized weights bf16 (pad rows = 0)
    float* __restrict__ pm, float* __restrict__ ps)   // [NT][B_ROWS]
{
    __shared__ __align__(16) uint16_t sA[128 * 64];
    __shared__ __align__(16) uint16_t sB[128 * 64];
    const int tid  = threadIdx.x;
    const int lane = tid & 63;
    const int wid  = tid >> 6;
    const int wm   = wid >> 1;         // 2x2 wave grid, each wave owns 64x64
    const int wn   = wid & 1;
    const int bid  = blockIdx.x;
    const int mtile = bid & 7;         // fastest-varying: 8 consecutive blocks share W tile (L2)
    const int ntile = bid >> 3;

    const uint16_t* Ab = A + (size_t)mtile * 128 * DIM;
    const uint16_t* Wb = W + (size_t)ntile * 128 * DIM;

    f32x4 acc[4][4] = {};

    const int srow = lane >> 3;        // 0..7: row within 8-row chunk
    const int scol = (lane & 7) * 8;   // bf16 col within 64

    for (int k0 = 0; k0 < DIM; k0 += 64) {
        #pragma unroll
        for (int c = 0; c < 4; ++c) {
            const int chunk = wid * 4 + c;         // 0..15, wave-uniform
            const int row   = chunk * 8 + srow;
            __builtin_amdgcn_global_load_lds(
                (const __attribute__((address_space(1))) uint32_t*)(Ab + (size_t)row * DIM + k0 + scol),
                (__attribute__((address_space(3))) uint32_t*)(sA + chunk * 512),
                16, 0, 0);
            __builtin_amdgcn_global_load_lds(
                (const __attribute__((address_space(1))) uint32_t*)(Wb + (size_t)row * DIM + k0 + scol),
                (__attribute__((address_space(3))) uint32_t*)(sB + chunk * 512),
                16, 0, 0);
        }
        __syncthreads();
        #pragma unroll
        for (int ks = 0; ks < 2; ++ks) {
            bf16x8 af[4], bfr[4];
            const int kb = ks * 32 + (lane >> 4) * 8;
            #pragma unroll
            for (int mi = 0; mi < 4; ++mi)
                af[mi] = *reinterpret_cast<const bf16x8*>(&sA[(wm*64 + mi*16 + (lane & 15)) * 64 + kb]);
            #pragma unroll
            for (int ni = 0; ni < 4; ++ni)
                bfr[ni] = *reinterpret_cast<const bf16x8*>(&sB[(wn*64 + ni*16 + (lane & 15)) * 64 + kb]);
            #pragma unroll
            for (int mi = 0; mi < 4; ++mi)
                #pragma unroll
                for (int ni = 0; ni < 4; ++ni)
                    acc[mi][ni] = __builtin_amdgcn_mfma_f32_16x16x32_bf16(af[mi], bfr[ni], acc[mi][ni], 0, 0, 0);
        }
        __syncthreads();
    }

    // epilogue: logits = 64*cos; per-row max & sumexp over this block's 128 columns
    float* red_m = reinterpret_cast<float*>(sA);   // [128][2]
    float* red_s = red_m + 256;
    #pragma unroll
    for (int mi = 0; mi < 4; ++mi) {
        #pragma unroll
        for (int r = 0; r < 4; ++r) {
            float v0 = acc[mi][0][r] * 64.0f;
            float v1 = acc[mi][1][r] * 64.0f;
            float v2 = acc[mi][2][r] * 64.0f;
            float v3 = acc[mi][3][r] * 64.0f;
            float mx = fmaxf(fmaxf(v0, v1), fmaxf(v2, v3));
            #pragma unroll
            for (int k = 1; k < 16; k <<= 1) mx = fmaxf(mx, __shfl_xor(mx, k));
            float s = __expf(v0 - mx) + __expf(v1 - mx) + __expf(v2 - mx) + __expf(v3 - mx);
            #pragma unroll
            for (int k = 1; k < 16; k <<= 1) s += __shfl_xor(s, k);
            const int rowl = wm * 64 + mi * 16 + (lane >> 4) * 4 + r;
            if ((lane & 15) == 0) { red_m[rowl * 2 + wn] = mx; red_s[rowl * 2 + wn] = s; }
        }
    }
    __syncthreads();
    if (tid < 128) {
        float m0 = red_m[tid * 2], m1 = red_m[tid * 2 + 1];
        float s0 = red_s[tid * 2], s1 = red_s[tid * 2 + 1];
        float Mx = fmaxf(m0, m1);
        float S  = s0 * __expf(m0 - Mx) + s1 * __expf(m1 - Mx);
        size_t idx = (size_t)ntile * B_ROWS + mtile * 128 + tid;
        pm[idx] = Mx; ps[idx] = S;
    }
}

// ---------- pass 3: per-row combine partials + exact margin/pad correction
__global__ __launch_bounds__(256) void finalize(
    const float* __restrict__ pm, const float* __restrict__ ps,
    const uint16_t* __restrict__ fb, const uint16_t* __restrict__ wb,
    const int* __restrict__ labels, float* __restrict__ row_loss)
{
    const int row = blockIdx.x;
    const int t   = threadIdx.x;      // 256
    const int lab = labels[row];

    // target cosine: dot(f_norm[row], w_norm[lab]) in f32 from bf16 inputs
    uint32_t fa = reinterpret_cast<const uint32_t*>(fb + (size_t)row * DIM)[t];
    uint32_t wa = reinterpret_cast<const uint32_t*>(wb + (size_t)lab * DIM)[t];
    float d = bf2f(fa & 0xffffu) * bf2f(wa & 0xffffu) + bf2f(fa >> 16) * bf2f(wa >> 16);
    #pragma unroll
    for (int k = 1; k < 64; k <<= 1) d += __shfl_xor(d, k);

    // online combine of NT partials (every thread gets >=3, so m is finite before wave-reduce)
    float m = -INFINITY, s = 0.0f;
    for (int i = t; i < NT; i += 256) {
        float pmi = pm[(size_t)i * B_ROWS + row];
        float psi = ps[(size_t)i * B_ROWS + row];
        float M2  = fmaxf(m, pmi);
        s = s * __expf(m - M2) + psi * __expf(pmi - M2);
        m = M2;
    }
    #pragma unroll
    for (int k = 1; k < 64; k <<= 1) {
        float om = __shfl_xor(m, k), os = __shfl_xor(s, k);
        float M2 = fmaxf(m, om);
        s = s * __expf(m - M2) + os * __expf(om - M2);
        m = M2;
    }
    __shared__ float sd[4], sm[4], ssm[4];
    if ((t & 63) == 0) { sd[t >> 6] = d; sm[t >> 6] = m; ssm[t >> 6] = s; }
    __syncthreads();
    if (t == 0) {
        float dt = sd[0] + sd[1] + sd[2] + sd[3];
        float Mx = fmaxf(fmaxf(sm[0], sm[1]), fmaxf(sm[2], sm[3]));
        float S  = ssm[0] * __expf(sm[0] - Mx) + ssm[1] * __expf(sm[1] - Mx)
                 + ssm[2] * __expf(sm[2] - Mx) + ssm[3] * __expf(sm[3] - Mx);
        float lt = 64.0f * dt;
        // swap unmargined target term for margined one; remove pad columns (logit 0) exactly
        S += expf(lt - 32.0f - Mx) - expf(lt - Mx) - (float)(C_PAD - C_CLS) * expf(-Mx);
        row_loss[row] = Mx + logf(S) - (lt - 32.0f);
    }
}

// ---------- pass 4: mean over rows
__global__ __launch_bounds__(256) void mean_k(const float* __restrict__ rl, float* __restrict__ out)
{
    const int t = threadIdx.x;
    float s = 0.0f;
    for (int i = t; i < B_ROWS; i += 256) s += rl[i];
    #pragma unroll
    for (int k = 1; k < 64; k <<= 1) s += __shfl_xor(s, k);
    __shared__ float r4[4];
    if ((t & 63) == 0) r4[t >> 6] = s;
    __syncthreads();
    if (t == 0) out[0] = (r4[0] + r4[1] + r4[2] + r4[3]) * (1.0f / B_ROWS);
}

extern "C" void kernel_launch(void* const* d_in, const int* in_sizes, int n_in,
                              void* d_out, int out_size, void* d_ws, size_t ws_size,
                              hipStream_t stream)
{
    const float* features = (const float*)d_in[0];
    const int*   labels   = (const int*)d_in[1];
    const float* weight   = (const float*)d_in[2];

    char* ws = (char*)d_ws;
    uint16_t* wb = (uint16_t*)ws;                                        // C_PAD * DIM bf16
    uint16_t* fb = (uint16_t*)(ws + (size_t)C_PAD * DIM * 2);            // B_ROWS * DIM bf16
    float*    pm = (float*)(ws + (size_t)C_PAD * DIM * 2 + (size_t)B_ROWS * DIM * 2);
    float*    ps = pm + (size_t)NT * B_ROWS;
    float*    rl = ps + (size_t)NT * B_ROWS;

    normalize_rows<<<C_PAD,  128, 0, stream>>>(weight,   wb, C_CLS);
    normalize_rows<<<B_ROWS, 128, 0, stream>>>(features, fb, B_ROWS);
    gemm_lse<<<NT * MT, 256, 0, stream>>>(fb, wb, pm, ps);
    finalize<<<B_ROWS, 256, 0, stream>>>(pm, ps, fb, wb, labels, rl);
    mean_k<<<1, 256, 0, stream>>>(rl, (float*)d_out);
}

// Round 3
// 229.336 us; speedup vs baseline: 1.3282x; 1.3282x over previous
//
#include <hip/hip_runtime.h>
#include <hip/hip_bf16.h>
#include <stdint.h>

#define B_ROWS 1024
#define DIM    512
#define C_CLS  100000
#define C_PAD  100352          // 8 XCDs * 98 ntiles * 128
#define NT     784             // C_PAD / 128
#define NT_PER_XCD 98
#define MT     8               // B_ROWS / 128
#define NPAD   (C_PAD - C_CLS) // 352 pad cols, logit 0

using f32x4  = __attribute__((ext_vector_type(4))) float;
using bf16x8 = __attribute__((ext_vector_type(8))) short;   // 8 bf16 (4 VGPRs)

static __device__ __forceinline__ float bf2f(uint32_t u) { return __uint_as_float(u << 16); }
static __device__ __forceinline__ uint32_t f2bf(float f) {
    uint32_t u = __float_as_uint(f);
    u += 0x7fffu + ((u >> 16) & 1u);          // round-to-nearest-even
    return u >> 16;
}

// ---------- pass 1: per-row L2 normalize (one wave per row), f32 -> bf16; pad rows zeroed
__global__ __launch_bounds__(256) void normalize_rows(
    const float* __restrict__ src, uint16_t* __restrict__ dst, int nvalid, int ntotal)
{
    const int row  = blockIdx.x * 4 + (threadIdx.x >> 6);
    const int lane = threadIdx.x & 63;
    if (row >= ntotal) return;
    uint4* d4 = reinterpret_cast<uint4*>(dst + (size_t)row * DIM);
    if (row >= nvalid) { d4[lane] = make_uint4(0u, 0u, 0u, 0u); return; }
    const float4* s4 = reinterpret_cast<const float4*>(src + (size_t)row * DIM);
    const float4 a = s4[lane * 2], b = s4[lane * 2 + 1];
    float ss = a.x*a.x + a.y*a.y + a.z*a.z + a.w*a.w
             + b.x*b.x + b.y*b.y + b.z*b.z + b.w*b.w;
    #pragma unroll
    for (int k = 1; k < 64; k <<= 1) ss += __shfl_xor(ss, k);
    const float inv = 1.0f / fmaxf(sqrtf(ss), 1e-12f);
    uint4 o;
    o.x = f2bf(a.x*inv) | (f2bf(a.y*inv) << 16);
    o.y = f2bf(a.z*inv) | (f2bf(a.w*inv) << 16);
    o.z = f2bf(b.x*inv) | (f2bf(b.y*inv) << 16);
    o.w = f2bf(b.z*inv) | (f2bf(b.w*inv) << 16);
    d4[lane] = o;
}

// ---------- pass 2: 128x128 bf16 MFMA tile, dbuf-prefetch, swizzled LDS,
//            fixed-shift (64) per-row sumexp partials over the tile's 128 cols
__global__ __launch_bounds__(256) void gemm_lse(
    const uint16_t* __restrict__ A,   // [B_ROWS][DIM]
    const uint16_t* __restrict__ W,   // [C_PAD][DIM]  (pad rows zero)
    float* __restrict__ ps)           // [NT][B_ROWS]
{
    __shared__ __align__(16) uint16_t sA[2][128 * 64];
    __shared__ __align__(16) uint16_t sB[2][128 * 64];
    const int tid  = threadIdx.x;
    const int lane = tid & 63;
    const int wid  = tid >> 6;
    const int wm   = wid >> 1;         // 2x2 wave grid, 64x64 each
    const int wn   = wid & 1;

    // XCD-bijective mapping: all 8 mtiles of one ntile run consecutively on ONE XCD
    const int b     = blockIdx.x;
    const int xcd   = b & 7;
    const int j     = b >> 3;          // 0..783 within XCD
    const int ntile = xcd * NT_PER_XCD + (j >> 3);
    const int mtile = j & 7;

    const uint16_t* Ab = A + (size_t)mtile * 128 * DIM;
    const uint16_t* Wb = W + (size_t)ntile * 128 * DIM;

    // staging geometry: each wave stages 4 chunks of 8 rows; lane -> (row, 16B unit)
    const int srow8 = lane >> 3;                 // row within chunk
    const int su    = (lane & 7) ^ srow8;        // pre-swizzled source 16B unit (rule #21)

    f32x4 acc[4][4] = {};

    auto stage = [&](int bufi, int k0) {
        #pragma unroll
        for (int c = 0; c < 4; ++c) {
            const int chunk = wid * 4 + c;       // wave-uniform
            const int row   = chunk * 8 + srow8;
            __builtin_amdgcn_global_load_lds(
                (const __attribute__((address_space(1))) uint32_t*)(Ab + (size_t)row * DIM + k0 + su * 8),
                (__attribute__((address_space(3))) uint32_t*)(&sA[bufi][chunk * 512]), 16, 0, 0);
            __builtin_amdgcn_global_load_lds(
                (const __attribute__((address_space(1))) uint32_t*)(Wb + (size_t)row * DIM + k0 + su * 8),
                (__attribute__((address_space(3))) uint32_t*)(&sB[bufi][chunk * 512]), 16, 0, 0);
        }
    };

    stage(0, 0);
    __syncthreads();                             // drain vmcnt(0): buf0 ready

    #pragma unroll 2
    for (int t = 0; t < 8; ++t) {
        const int cur = t & 1;
        if (t < 7) stage(cur ^ 1, (t + 1) * 64); // issue next-tile loads FIRST (overlap)
        #pragma unroll
        for (int ks = 0; ks < 2; ++ks) {
            bf16x8 af[4], bfr[4];
            #pragma unroll
            for (int mi = 0; mi < 4; ++mi) {
                const int row  = wm * 64 + mi * 16 + (lane & 15);
                const int unit = ((ks * 4) | (lane >> 4)) ^ (row & 7);   // swizzled read
                af[mi] = *reinterpret_cast<const bf16x8*>(&sA[cur][row * 64 + unit * 8]);
            }
            #pragma unroll
            for (int ni = 0; ni < 4; ++ni) {
                const int row  = wn * 64 + ni * 16 + (lane & 15);
                const int unit = ((ks * 4) | (lane >> 4)) ^ (row & 7);
                bfr[ni] = *reinterpret_cast<const bf16x8*>(&sB[cur][row * 64 + unit * 8]);
            }
            #pragma unroll
            for (int mi = 0; mi < 4; ++mi)
                #pragma unroll
                for (int ni = 0; ni < 4; ++ni)
                    acc[mi][ni] = __builtin_amdgcn_mfma_f32_16x16x32_bf16(af[mi], bfr[ni], acc[mi][ni], 0, 0, 0);
        }
        __syncthreads();                         // drains vmcnt(0): next buf ready, cur reads done
    }

    // epilogue: logits = 64*cos in [-64,64]; fixed shift 64 -> sum exp(logit-64), no max pass
    float* red = reinterpret_cast<float*>(sA);   // [128][2]
    #pragma unroll
    for (int mi = 0; mi < 4; ++mi) {
        #pragma unroll
        for (int r = 0; r < 4; ++r) {
            float s = __expf(fmaf(acc[mi][0][r], 64.0f, -64.0f))
                    + __expf(fmaf(acc[mi][1][r], 64.0f, -64.0f))
                    + __expf(fmaf(acc[mi][2][r], 64.0f, -64.0f))
                    + __expf(fmaf(acc[mi][3][r], 64.0f, -64.0f));
            #pragma unroll
            for (int k = 1; k < 16; k <<= 1) s += __shfl_xor(s, k);
            if ((lane & 15) == 0) {
                const int rowl = wm * 64 + mi * 16 + (lane >> 4) * 4 + r;
                red[rowl * 2 + wn] = s;
            }
        }
    }
    __syncthreads();
    if (tid < 128)
        ps[(size_t)ntile * B_ROWS + mtile * 128 + tid] = red[tid * 2] + red[tid * 2 + 1];
}

// ---------- pass 3: per-row sum of partials + exact margin/pad correction
__global__ __launch_bounds__(256) void finalize(
    const float* __restrict__ ps,
    const uint16_t* __restrict__ fb, const uint16_t* __restrict__ wb,
    const int* __restrict__ labels, float* __restrict__ row_loss)
{
    const int row = blockIdx.x;
    const int t   = threadIdx.x;      // 256
    const int lab = labels[row];

    // target cosine in f32 from the same bf16 vectors the GEMM used
    uint32_t fa = reinterpret_cast<const uint32_t*>(fb + (size_t)row * DIM)[t];
    uint32_t wa = reinterpret_cast<const uint32_t*>(wb + (size_t)lab * DIM)[t];
    float d = bf2f(fa & 0xffffu) * bf2f(wa & 0xffffu) + bf2f(fa >> 16) * bf2f(wa >> 16);
    #pragma unroll
    for (int k = 1; k < 64; k <<= 1) d += __shfl_xor(d, k);

    float s = 0.0f;
    for (int i = t; i < NT; i += 256) s += ps[(size_t)i * B_ROWS + row];
    #pragma unroll
    for (int k = 1; k < 64; k <<= 1) s += __shfl_xor(s, k);

    __shared__ float sd[4], ssm[4];
    if ((t & 63) == 0) { sd[t >> 6] = d; ssm[t >> 6] = s; }
    __syncthreads();
    if (t == 0) {
        const float dt = sd[0] + sd[1] + sd[2] + sd[3];
        float S = ssm[0] + ssm[1] + ssm[2] + ssm[3];
        const float lt = 64.0f * dt;
        // swap unmargined target term for margined one; remove pad columns (logit 0)
        S += expf(lt - 96.0f) - expf(lt - 64.0f) - (float)NPAD * expf(-64.0f);
        row_loss[row] = 64.0f + logf(S) - (lt - 32.0f);
    }
}

// ---------- pass 4: mean over rows
__global__ __launch_bounds__(256) void mean_k(const float* __restrict__ rl, float* __restrict__ out)
{
    const int t = threadIdx.x;
    float s = 0.0f;
    for (int i = t; i < B_ROWS; i += 256) s += rl[i];
    #pragma unroll
    for (int k = 1; k < 64; k <<= 1) s += __shfl_xor(s, k);
    __shared__ float r4[4];
    if ((t & 63) == 0) r4[t >> 6] = s;
    __syncthreads();
    if (t == 0) out[0] = (r4[0] + r4[1] + r4[2] + r4[3]) * (1.0f / B_ROWS);
}

extern "C" void kernel_launch(void* const* d_in, const int* in_sizes, int n_in,
                              void* d_out, int out_size, void* d_ws, size_t ws_size,
                              hipStream_t stream)
{
    const float* features = (const float*)d_in[0];
    const int*   labels   = (const int*)d_in[1];
    const float* weight   = (const float*)d_in[2];

    char* ws = (char*)d_ws;
    uint16_t* wb = (uint16_t*)ws;                                        // C_PAD * DIM bf16
    uint16_t* fb = (uint16_t*)(ws + (size_t)C_PAD * DIM * 2);            // B_ROWS * DIM bf16
    float*    psum = (float*)(ws + (size_t)C_PAD * DIM * 2 + (size_t)B_ROWS * DIM * 2);
    float*    rl = psum + (size_t)NT * B_ROWS;

    normalize_rows<<<C_PAD / 4, 256, 0, stream>>>(weight, wb, C_CLS, C_PAD);
    normalize_rows<<<B_ROWS / 4, 256, 0, stream>>>(features, fb, B_ROWS, B_ROWS);
    gemm_lse<<<NT * MT, 256, 0, stream>>>(fb, wb, psum);
    finalize<<<B_ROWS, 256, 0, stream>>>(psum, fb, wb, labels, rl);
    mean_k<<<1, 256, 0, stream>>>(rl, (float*)d_out);
}

// Round 4
// 193.867 us; speedup vs baseline: 1.5712x; 1.1830x over previous
//
#include <hip/hip_runtime.h>
#include <hip/hip_bf16.h>
#include <stdint.h>

#define B_ROWS 1024
#define DIM    512
#define C_CLS  100000
#define C_PAD  100352          // 8 XCDs * 49 ntiles * 256
#define NT     392             // C_PAD / 256
#define NT_PER_XCD 49
#define MT     4               // B_ROWS / 256
#define NPAD   (C_PAD - C_CLS) // 352 pad cols, logit 0

using f32x4  = __attribute__((ext_vector_type(4))) float;
using bf16x8 = __attribute__((ext_vector_type(8))) short;   // 8 bf16 (4 VGPRs)

#define AS1(p) ((const __attribute__((address_space(1))) uint32_t*)(p))
#define AS3(p) ((__attribute__((address_space(3))) uint32_t*)(p))
#define SBAR()   __builtin_amdgcn_s_barrier()
#define SCHED0() __builtin_amdgcn_sched_barrier(0)
#define LGKM0()  asm volatile("s_waitcnt lgkmcnt(0)" ::: "memory")
#define VMCNT6() asm volatile("s_waitcnt vmcnt(6)" ::: "memory")
#define VMCNT0() asm volatile("s_waitcnt vmcnt(0)" ::: "memory")

static __device__ __forceinline__ float bf2f(uint32_t u) { return __uint_as_float(u << 16); }
static __device__ __forceinline__ uint32_t f2bf(float f) {
    uint32_t u = __float_as_uint(f);
    u += 0x7fffu + ((u >> 16) & 1u);          // round-to-nearest-even
    return u >> 16;
}

// ---------- pass 1: per-row L2 normalize (one wave per row), f32 -> bf16; pad rows zeroed
__global__ __launch_bounds__(256) void normalize_rows(
    const float* __restrict__ src, uint16_t* __restrict__ dst, int nvalid, int ntotal)
{
    const int row  = blockIdx.x * 4 + (threadIdx.x >> 6);
    const int lane = threadIdx.x & 63;
    if (row >= ntotal) return;
    uint4* d4 = reinterpret_cast<uint4*>(dst + (size_t)row * DIM);
    if (row >= nvalid) { d4[lane] = make_uint4(0u, 0u, 0u, 0u); return; }
    const float4* s4 = reinterpret_cast<const float4*>(src + (size_t)row * DIM);
    const float4 a = s4[lane * 2], b = s4[lane * 2 + 1];
    float ss = a.x*a.x + a.y*a.y + a.z*a.z + a.w*a.w
             + b.x*b.x + b.y*b.y + b.z*b.z + b.w*b.w;
    #pragma unroll
    for (int k = 1; k < 64; k <<= 1) ss += __shfl_xor(ss, k);
    const float inv = 1.0f / fmaxf(sqrtf(ss), 1e-12f);
    uint4 o;
    o.x = f2bf(a.x*inv) | (f2bf(a.y*inv) << 16);
    o.y = f2bf(a.z*inv) | (f2bf(a.w*inv) << 16);
    o.z = f2bf(b.x*inv) | (f2bf(b.y*inv) << 16);
    o.w = f2bf(b.z*inv) | (f2bf(b.w*inv) << 16);
    d4[lane] = o;
}

// ---------- pass 2: 256x256 bf16 MFMA tile, 8-phase counted-vmcnt schedule (T3+T4+T5),
//            fixed-shift (64) per-row sumexp partials over the tile's 256 cols
__global__ __launch_bounds__(512, 2) void gemm_lse(
    const uint16_t* __restrict__ A,   // [B_ROWS][DIM]
    const uint16_t* __restrict__ W,   // [C_PAD][DIM]  (pad rows zero)
    float* __restrict__ ps)           // [NT][B_ROWS]
{
    // [buf][region: A0(rows0-127), A1, B0(cols0-127), B1][128*64 bf16], 128 KiB
    __shared__ __align__(16) uint16_t lds[2][4][128 * 64];

    const int tid  = threadIdx.x;
    const int lane = tid & 63;
    const int wid  = tid >> 6;       // 8 waves: 2M x 4N
    const int wr   = wid >> 2;       // 0..1  (128 rows each)
    const int wc   = wid & 3;        // 0..3  (64 cols each)

    const int b     = blockIdx.x;
    const int xcd   = b & 7;
    const int j     = b >> 3;        // 0..195 within XCD
    const int ntile = xcd * NT_PER_XCD + (j >> 2);
    const int mtile = j & 3;

    const uint16_t* Abase = A + (size_t)mtile * 256 * DIM;
    const uint16_t* Bbase = W + (size_t)ntile * 256 * DIM;

    // staging geometry: half-tile = 128 rows x 64 k = 16KB; 2 gload_lds(16B)/thread
    const int r0 = tid >> 3;
    const int us = (tid & 7) ^ (r0 & 7);      // pre-swizzled source unit (rule #21)
    const int r1 = r0 + 64;                   // (r1&7)==(r0&7) -> same us

    auto stage = [&](int kt, int h) {
        const uint16_t* src = ((h < 2) ? Abase : Bbase)
                            + (size_t)((h & 1) * 128) * DIM + kt * 64;
        uint16_t* dst = &lds[kt & 1][h][0];
        __builtin_amdgcn_global_load_lds(AS1(src + (size_t)r0 * DIM + us * 8),
                                         AS3(dst + tid * 8), 16, 0, 0);
        __builtin_amdgcn_global_load_lds(AS1(src + (size_t)r1 * DIM + us * 8),
                                         AS3(dst + (tid + 512) * 8), 16, 0, 0);
    };

    const int l15 = lane & 15;
    const int uhi = lane >> 4;
    const int ux  = lane & 7;

    bf16x8 aF[8][2], bF[4][2];
    f32x4 acc[8][4] = {};

    auto ldA = [&](int buf, int mi, int ks) {
        const int row  = mi * 16 + l15;
        const int unit = ((ks << 2) | uhi) ^ ux;
        return *reinterpret_cast<const bf16x8*>(&lds[buf][wr][row * 64 + unit * 8]);
    };
    auto ldB = [&](int buf, int ni, int ks) {
        const int row  = (wc & 1) * 64 + ni * 16 + l15;
        const int unit = ((ks << 2) | uhi) ^ ux;
        return *reinterpret_cast<const bf16x8*>(&lds[buf][2 + (wc >> 1)][row * 64 + unit * 8]);
    };
    auto rdA = [&](int buf) {
        #pragma unroll
        for (int mi = 0; mi < 8; ++mi) { aF[mi][0] = ldA(buf, mi, 0); aF[mi][1] = ldA(buf, mi, 1); }
    };
    auto rdB01 = [&](int buf) {
        bF[0][0]=ldB(buf,0,0); bF[0][1]=ldB(buf,0,1); bF[1][0]=ldB(buf,1,0); bF[1][1]=ldB(buf,1,1);
    };
    auto rdB23 = [&](int buf) {
        bF[2][0]=ldB(buf,2,0); bF[2][1]=ldB(buf,2,1); bF[3][0]=ldB(buf,3,0); bF[3][1]=ldB(buf,3,1);
    };
    auto quad = [&](int mh, int nh) {
        __builtin_amdgcn_s_setprio(1);
        #pragma unroll
        for (int m2 = 0; m2 < 4; ++m2)
            #pragma unroll
            for (int n2 = 0; n2 < 2; ++n2)
                #pragma unroll
                for (int ks = 0; ks < 2; ++ks)
                    acc[mh*4+m2][nh*2+n2] = __builtin_amdgcn_mfma_f32_16x16x32_bf16(
                        aF[mh*4+m2][ks], bF[nh*2+n2][ks], acc[mh*4+m2][nh*2+n2], 0, 0, 0);
        __builtin_amdgcn_s_setprio(0);
    };

    // prologue: kt0 (4 HT) + kt1 (3 HT); vmcnt(6) -> kt0 fully arrived
    stage(0,0); stage(0,1); stage(0,2); stage(0,3);
    stage(1,0); stage(1,1); stage(1,2);
    VMCNT6(); SCHED0(); SBAR();

    // steady iterations: compute kt t (buf0) at p0-3, kt t+1 (buf1) at p4-7
    #pragma unroll 1
    for (int t = 0; t < 6; t += 2) {
        // p0
        rdA(0); rdB01(0); stage(t+1, 3);
        SCHED0(); SBAR(); LGKM0(); SCHED0();
        quad(0,0); SCHED0(); SBAR();
        // p1
        rdB23(0); stage(t+2, 0);
        SCHED0(); SBAR(); LGKM0(); SCHED0();
        quad(0,1); SCHED0(); SBAR();
        // p2
        stage(t+2, 1);
        SCHED0(); SBAR();
        quad(1,0); SCHED0(); SBAR();
        // p3
        stage(t+2, 2); VMCNT6();
        SCHED0(); SBAR();
        quad(1,1); SCHED0(); SBAR();
        // p4
        rdA(1); rdB01(1); stage(t+2, 3);
        SCHED0(); SBAR(); LGKM0(); SCHED0();
        quad(0,0); SCHED0(); SBAR();
        // p5
        rdB23(1); stage(t+3, 0);
        SCHED0(); SBAR(); LGKM0(); SCHED0();
        quad(0,1); SCHED0(); SBAR();
        // p6
        stage(t+3, 1);
        SCHED0(); SBAR();
        quad(1,0); SCHED0(); SBAR();
        // p7
        stage(t+3, 2); VMCNT6();
        SCHED0(); SBAR();
        quad(1,1); SCHED0(); SBAR();
    }

    // tail: kt6 (buf0) + kt7 (buf1); only kt7.B1 left to stage; drain at p3
    rdA(0); rdB01(0); stage(7, 3);
    SCHED0(); SBAR(); LGKM0(); SCHED0();
    quad(0,0); SCHED0(); SBAR();
    rdB23(0);
    SCHED0(); SBAR(); LGKM0(); SCHED0();
    quad(0,1); SCHED0(); SBAR();
    quad(1,0); SCHED0(); SBAR();
    VMCNT0(); SCHED0(); SBAR();
    quad(1,1); SCHED0(); SBAR();
    rdA(1); rdB01(1);
    SCHED0(); SBAR(); LGKM0(); SCHED0();
    quad(0,0); SCHED0(); SBAR();
    rdB23(1);
    LGKM0(); SCHED0();
    quad(0,1);
    quad(1,0);
    quad(1,1);

    // epilogue: logits = 64*cos in [-64,64]; fixed shift 64 -> sum exp(logit-64)
    __syncthreads();                               // all LDS reads done; reuse as red buffer
    float* red = reinterpret_cast<float*>(&lds[0][0][0]);   // [256 rows][4 wc]
    #pragma unroll
    for (int mi = 0; mi < 8; ++mi) {
        #pragma unroll
        for (int r = 0; r < 4; ++r) {
            float s = __expf(fmaf(acc[mi][0][r], 64.0f, -64.0f))
                    + __expf(fmaf(acc[mi][1][r], 64.0f, -64.0f))
                    + __expf(fmaf(acc[mi][2][r], 64.0f, -64.0f))
                    + __expf(fmaf(acc[mi][3][r], 64.0f, -64.0f));
            #pragma unroll
            for (int k = 1; k < 16; k <<= 1) s += __shfl_xor(s, k);
            if (l15 == 0) red[(wr * 128 + mi * 16 + uhi * 4 + r) * 4 + wc] = s;
        }
    }
    __syncthreads();
    if (tid < 256)
        ps[(size_t)ntile * B_ROWS + mtile * 256 + tid] =
            red[tid*4+0] + red[tid*4+1] + red[tid*4+2] + red[tid*4+3];
}

// ---------- pass 3: per-row sum of partials + exact margin/pad correction
__global__ __launch_bounds__(256) void finalize(
    const float* __restrict__ ps,
    const uint16_t* __restrict__ fb, const uint16_t* __restrict__ wb,
    const int* __restrict__ labels, float* __restrict__ row_loss)
{
    const int row = blockIdx.x;
    const int t   = threadIdx.x;      // 256
    const int lab = labels[row];

    // target cosine in f32 from the same bf16 vectors the GEMM used
    uint32_t fa = reinterpret_cast<const uint32_t*>(fb + (size_t)row * DIM)[t];
    uint32_t wa = reinterpret_cast<const uint32_t*>(wb + (size_t)lab * DIM)[t];
    float d = bf2f(fa & 0xffffu) * bf2f(wa & 0xffffu) + bf2f(fa >> 16) * bf2f(wa >> 16);
    #pragma unroll
    for (int k = 1; k < 64; k <<= 1) d += __shfl_xor(d, k);

    float s = 0.0f;
    for (int i = t; i < NT; i += 256) s += ps[(size_t)i * B_ROWS + row];
    #pragma unroll
    for (int k = 1; k < 64; k <<= 1) s += __shfl_xor(s, k);

    __shared__ float sd[4], ssm[4];
    if ((t & 63) == 0) { sd[t >> 6] = d; ssm[t >> 6] = s; }
    __syncthreads();
    if (t == 0) {
        const float dt = sd[0] + sd[1] + sd[2] + sd[3];
        float S = ssm[0] + ssm[1] + ssm[2] + ssm[3];
        const float lt = 64.0f * dt;
        // swap unmargined target term for margined one; remove pad columns (logit 0)
        S += expf(lt - 96.0f) - expf(lt - 64.0f) - (float)NPAD * expf(-64.0f);
        row_loss[row] = 64.0f + logf(S) - (lt - 32.0f);
    }
}

// ---------- pass 4: mean over rows
__global__ __launch_bounds__(256) void mean_k(const float* __restrict__ rl, float* __restrict__ out)
{
    const int t = threadIdx.x;
    float s = 0.0f;
    for (int i = t; i < B_ROWS; i += 256) s += rl[i];
    #pragma unroll
    for (int k = 1; k < 64; k <<= 1) s += __shfl_xor(s, k);
    __shared__ float r4[4];
    if ((t & 63) == 0) r4[t >> 6] = s;
    __syncthreads();
    if (t == 0) out[0] = (r4[0] + r4[1] + r4[2] + r4[3]) * (1.0f / B_ROWS);
}

extern "C" void kernel_launch(void* const* d_in, const int* in_sizes, int n_in,
                              void* d_out, int out_size, void* d_ws, size_t ws_size,
                              hipStream_t stream)
{
    const float* features = (const float*)d_in[0];
    const int*   labels   = (const int*)d_in[1];
    const float* weight   = (const float*)d_in[2];

    char* ws = (char*)d_ws;
    uint16_t* wb = (uint16_t*)ws;                                        // C_PAD * DIM bf16
    uint16_t* fb = (uint16_t*)(ws + (size_t)C_PAD * DIM * 2);            // B_ROWS * DIM bf16
    float*    psum = (float*)(ws + (size_t)C_PAD * DIM * 2 + (size_t)B_ROWS * DIM * 2);
    float*    rl = psum + (size_t)NT * B_ROWS;

    normalize_rows<<<C_PAD / 4, 256, 0, stream>>>(weight, wb, C_CLS, C_PAD);
    normalize_rows<<<B_ROWS / 4, 256, 0, stream>>>(features, fb, B_ROWS, B_ROWS);
    gemm_lse<<<NT * MT, 512, 0, stream>>>(fb, wb, psum);
    finalize<<<B_ROWS, 256, 0, stream>>>(psum, fb, wb, labels, rl);
    mean_k<<<1, 256, 0, stream>>>(rl, (float*)d_out);
}